// Round 2
// baseline (104154.993 us; speedup 1.0000x reference)
//
#include <hip/hip_runtime.h>
#include <hip/hip_cooperative_groups.h>

namespace cg = cooperative_groups;

// Problem constants
constexpr int BB   = 64;     // batch
constexpr int HH   = 256;    // hidden (H)
constexpr int PP   = 128;    // prenet out
constexpr int MM   = 512;    // memory length
constexpr int NM   = 80;     // num mels
constexpr int RR   = 5;      // outputs per step
constexpr int TIN  = 2000;   // input time
constexpr int NSTEP= 400;    // decoder steps
constexpr int OUTJ = 400;    // NM*RR

struct Params {
  const float *mem, *W2, *v;
  const float *a_wih, *a_whh, *a_bih, *a_bhh;
  const float *g1_wih, *g1_whh, *g1_bih, *g1_bhh;
  const float *g2_wih, *g2_whh, *g2_bih, *g2_bhh;
  const float *proj_w, *proj_b, *out_w, *out_b;
  const float *tf, *keys;
  float *scores, *ctx, *d0, *d1, *w2d;
  float *g1in, *g2in, *g1h0, *g1h1, *g2h0, *g2h1, *bf;
  float *out;
};

__device__ __forceinline__ float sigf(float x)  { return 1.0f / (1.0f + __expf(-x)); }
__device__ __forceinline__ float tanhfast(float x) { return 1.0f - 2.0f / (1.0f + __expf(2.0f * x)); }

// ---------------- prenet: only the 400 consumed frames ----------------
__global__ void __launch_bounds__(128) prenet_kernel(
    const float* __restrict__ din, const float* __restrict__ fc1w, const float* __restrict__ fc1b,
    const float* __restrict__ fc2w, const float* __restrict__ fc2b, float* __restrict__ tf) {
  int t = blockIdx.x, b = blockIdx.y, tid = threadIdx.x;
  __shared__ float x[NM];
  __shared__ float h1[256];
  if (tid < NM) x[tid] = din[(size_t)b * NM * TIN + (size_t)tid * TIN + t * RR];
  __syncthreads();
  for (int o = tid; o < 256; o += 128) {
    float a = fc1b[o];
    const float* w = fc1w + o * NM;
    for (int k = 0; k < NM; ++k) a += x[k] * w[k];
    h1[o] = fmaxf(a, 0.f);
  }
  __syncthreads();
  {
    int o = tid;
    float a = fc2b[o];
    const float* w = fc2w + o * 256;
    for (int k = 0; k < 256; ++k) a += h1[k] * w[k];
    tf[((size_t)t * BB + b) * PP + o] = fmaxf(a, 0.f);
  }
}

// ---------------- keys = memory @ W1^T ----------------
__global__ void __launch_bounds__(256) keys_kernel(
    const float* __restrict__ mem, const float* __restrict__ W1, float* __restrict__ keys) {
  int blk = blockIdx.x;
  int b = blk >> 6, mc = blk & 63, m0 = mc * 8, tid = threadIdx.x;
  __shared__ float sm[8 * 256];
  for (int i = tid; i < 2048; i += 256)
    sm[i] = mem[((size_t)b * MM + m0 + (i >> 8)) * HH + (i & 255)];
  __syncthreads();
  float acc[8] = {0, 0, 0, 0, 0, 0, 0, 0};
  const float* w = W1 + (size_t)tid * 256;
  for (int k = 0; k < 256; ++k) {
    float wk = w[k];
#pragma unroll
    for (int r = 0; r < 8; ++r) acc[r] += sm[r * 256 + k] * wk;
  }
  for (int r = 0; r < 8; ++r)
    keys[((size_t)b * MM + m0 + r) * HH + tid] = acc[r];
}

// ---------------- cooperative decoder jobs ----------------

// blocks [0,128): one score per thread
__device__ void job_scores(const Params& p) {
  int idx = blockIdx.x * 256 + threadIdx.x;       // [0, 32768)
  int b = idx >> 9, m = idx & 511;
  const float4* k4 = (const float4*)(p.keys + ((size_t)(b * MM + m)) * HH);
  const float4* w4 = (const float4*)(p.w2d + b * HH);
  const float4* v4 = (const float4*)p.v;
  float s = 0.f;
  for (int k = 0; k < 64; ++k) {
    float4 a = k4[k], c = w4[k], vv = v4[k];
    s += vv.x * tanhfast(a.x + c.x);
    s += vv.y * tanhfast(a.y + c.y);
    s += vv.z * tanhfast(a.z + c.z);
    s += vv.w * tanhfast(a.w + c.w);
  }
  p.scores[idx] = s;
}

// blocks [128,256): out projection for step tprev (j*64+b mapping → weight row broadcast)
__device__ void job_out(const Params& p, int tprev) {
  int idx = (blockIdx.x - 128) * 256 + threadIdx.x;   // [0, 32768), active < 25600
  if (idx >= BB * OUTJ) return;
  int j = idx >> 6, b = idx & 63;
  const float4* w4 = (const float4*)(p.out_w + (size_t)j * HH);
  const float4* x4 = (const float4*)(p.bf + b * HH);
  float a = p.out_b[j];
  for (int k = 0; k < 64; ++k) {
    float4 w = w4[k], x = x4[k];
    a += w.x * x.x + w.y * x.y + w.z * x.z + w.w * x.w;
  }
  int mel = j / RR, r = j % RR;
  p.out[(size_t)b * NM * TIN + (size_t)mel * TIN + tprev * RR + r] = a;
}

// all 256 blocks: (b, htile) → softmax (redundant per-block stats) + context tile
__device__ void job_ctx(const Params& p) {
  int b = blockIdx.x >> 2, ht = blockIdx.x & 3, tid = threadIdx.x;
  __shared__ float sw[512];
  __shared__ float red[256];
  float s0 = p.scores[b * MM + tid];
  float s1 = p.scores[b * MM + 256 + tid];
  red[tid] = fmaxf(s0, s1);
  __syncthreads();
  for (int o = 128; o > 0; o >>= 1) {
    if (tid < o) red[tid] = fmaxf(red[tid], red[tid + o]);
    __syncthreads();
  }
  float rmax = red[0];
  __syncthreads();
  float e0 = __expf(s0 - rmax), e1 = __expf(s1 - rmax);
  red[tid] = e0 + e1;
  __syncthreads();
  for (int o = 128; o > 0; o >>= 1) {
    if (tid < o) red[tid] += red[tid + o];
    __syncthreads();
  }
  float inv = 1.0f / red[0];
  __syncthreads();
  sw[tid] = e0 * inv;
  sw[tid + 256] = e1 * inv;
  __syncthreads();
  int hl = tid & 63, mc = tid >> 6;       // mc in [0,4)
  int h = ht * 64 + hl;
  float acc = 0.f;
  const float* mbase = p.mem + (size_t)b * MM * HH + h;
  for (int m = mc * 128; m < mc * 128 + 128; ++m)
    acc += sw[m] * mbase[(size_t)m * HH];
  red[tid] = acc;
  __syncthreads();
  if (tid < 64) {
    float v = red[tid] + red[tid + 64] + red[tid + 128] + red[tid + 192];
    p.ctx[b * HH + ht * 64 + tid] = v;
  }
  __syncthreads();
}

// blocks [0,128): g1in = concat(d,ctx) @ proj^T + proj_b   (tpo=2, oidx=h*64+b)
__device__ void job_g1in(const Params& p, const float* __restrict__ dcur) {
  int slot = blockIdx.x * 256 + threadIdx.x;   // [0, 32768)
  int oidx = slot >> 1, part = slot & 1;
  int h = oidx >> 6, b = oidx & 63;
  const float4* pr = (const float4*)(p.proj_w + (size_t)h * 512 + part * 256);
  const float4* u4 = (const float4*)((part == 0 ? dcur : p.ctx) + b * HH);
  float acc = 0.f;
  for (int k = 0; k < 64; ++k) {
    float4 w = pr[k], u = u4[k];
    acc += w.x * u.x + w.y * u.y + w.z * u.z + w.w * u.w;
  }
  acc += __shfl_xor(acc, 1);
  if (!part) p.g1in[b * HH + h] = acc + p.proj_b[h];
}

// 128 blocks starting at `base`: attention GRU d_next = gru(x[tn], d_read)  (tpo=2)
__device__ void job_attn_gru(const Params& p, int tn, const float* __restrict__ dread,
                             float* __restrict__ dwrite, int base) {
  int slot = (blockIdx.x - base) * 256 + threadIdx.x;  // [0, 32768)
  int oidx = slot >> 1, part = slot & 1;
  int h = oidx >> 6, b = oidx & 63;
  const float* xr = p.tf + ((size_t)tn * BB + b) * PP;
  const float* dr = dread + b * HH;
  float ir = 0, iz = 0, inn = 0, hr = 0, hz = 0, hn = 0;
  {
    const float4* x4 = (const float4*)(xr + part * 64);
    const float4* wr = (const float4*)(p.a_wih + (size_t)(0   + h) * PP + part * 64);
    const float4* wz = (const float4*)(p.a_wih + (size_t)(256 + h) * PP + part * 64);
    const float4* wn = (const float4*)(p.a_wih + (size_t)(512 + h) * PP + part * 64);
    for (int k = 0; k < 16; ++k) {
      float4 x = x4[k], a = wr[k], c = wz[k], e = wn[k];
      ir += x.x * a.x + x.y * a.y + x.z * a.z + x.w * a.w;
      iz += x.x * c.x + x.y * c.y + x.z * c.z + x.w * c.w;
      inn += x.x * e.x + x.y * e.y + x.z * e.z + x.w * e.w;
    }
  }
  {
    const float4* d4 = (const float4*)(dr + part * 128);
    const float4* ur = (const float4*)(p.a_whh + (size_t)(0   + h) * HH + part * 128);
    const float4* uz = (const float4*)(p.a_whh + (size_t)(256 + h) * HH + part * 128);
    const float4* un = (const float4*)(p.a_whh + (size_t)(512 + h) * HH + part * 128);
    for (int k = 0; k < 32; ++k) {
      float4 d = d4[k], a = ur[k], c = uz[k], e = un[k];
      hr += d.x * a.x + d.y * a.y + d.z * a.z + d.w * a.w;
      hz += d.x * c.x + d.y * c.y + d.z * c.z + d.w * c.w;
      hn += d.x * e.x + d.y * e.y + d.z * e.z + d.w * e.w;
    }
  }
  ir += __shfl_xor(ir, 1); iz += __shfl_xor(iz, 1); inn += __shfl_xor(inn, 1);
  hr += __shfl_xor(hr, 1); hz += __shfl_xor(hz, 1); hn += __shfl_xor(hn, 1);
  float r = sigf(ir + p.a_bih[h] + hr + p.a_bhh[h]);
  float z = sigf(iz + p.a_bih[256 + h] + hz + p.a_bhh[256 + h]);
  float n = tanhfast(inn + p.a_bih[512 + h] + r * (hn + p.a_bhh[512 + h]));
  if (!part) dwrite[b * HH + h] = (1.f - z) * n + z * dr[h];
}

// 64 blocks starting at `base`: w2d = d_new @ W2^T  (oidx=h*64+b)
__device__ void job_w2d(const Params& p, const float* __restrict__ dnew, int base) {
  int oidx = (blockIdx.x - base) * 256 + threadIdx.x;  // [0, 16384)
  int h = oidx >> 6, b = oidx & 63;
  const float4* w4 = (const float4*)(p.W2 + (size_t)h * HH);
  const float4* d4 = (const float4*)(dnew + b * HH);
  float acc = 0.f;
  for (int k = 0; k < 64; ++k) {
    float4 w = w4[k], d = d4[k];
    acc += w.x * d.x + w.y * d.y + w.z * d.z + w.w * d.w;
  }
  p.w2d[b * HH + h] = acc;
}

// generic GRU combine over x-input `xin` (len 256) and hidden `hold`, tpo = 2 or 4
template <int TPO>
__device__ void job_gru_comb(const float* __restrict__ xin, const float* __restrict__ hold,
                             const float* __restrict__ wih, const float* __restrict__ whh,
                             const float* __restrict__ bih, const float* __restrict__ bhh,
                             float* __restrict__ hnew, float* __restrict__ sum_out) {
  int slot = blockIdx.x * 256 + threadIdx.x;
  int oidx = slot / TPO, part = slot % TPO;
  int h = oidx >> 6, b = oidx & 63;
  constexpr int KW = 256 / TPO;   // per-part k width
  const float* xr = xin + b * HH;
  const float* hrw = hold + b * HH;
  float ir = 0, iz = 0, inn = 0, hr = 0, hz = 0, hn = 0;
  {
    const float4* x4 = (const float4*)(xr + part * KW);
    const float4* d4 = (const float4*)(hrw + part * KW);
    const float4* wr = (const float4*)(wih + (size_t)(0   + h) * HH + part * KW);
    const float4* wz = (const float4*)(wih + (size_t)(256 + h) * HH + part * KW);
    const float4* wn = (const float4*)(wih + (size_t)(512 + h) * HH + part * KW);
    const float4* ur = (const float4*)(whh + (size_t)(0   + h) * HH + part * KW);
    const float4* uz = (const float4*)(whh + (size_t)(256 + h) * HH + part * KW);
    const float4* un = (const float4*)(whh + (size_t)(512 + h) * HH + part * KW);
    for (int k = 0; k < KW / 4; ++k) {
      float4 x = x4[k], d = d4[k];
      float4 a = wr[k], c = wz[k], e = wn[k];
      ir += x.x * a.x + x.y * a.y + x.z * a.z + x.w * a.w;
      iz += x.x * c.x + x.y * c.y + x.z * c.z + x.w * c.w;
      inn += x.x * e.x + x.y * e.y + x.z * e.z + x.w * e.w;
      a = ur[k]; c = uz[k]; e = un[k];
      hr += d.x * a.x + d.y * a.y + d.z * a.z + d.w * a.w;
      hz += d.x * c.x + d.y * c.y + d.z * c.z + d.w * c.w;
      hn += d.x * e.x + d.y * e.y + d.z * e.z + d.w * e.w;
    }
  }
  ir += __shfl_xor(ir, 1); iz += __shfl_xor(iz, 1); inn += __shfl_xor(inn, 1);
  hr += __shfl_xor(hr, 1); hz += __shfl_xor(hz, 1); hn += __shfl_xor(hn, 1);
  if (TPO == 4) {
    ir += __shfl_xor(ir, 2); iz += __shfl_xor(iz, 2); inn += __shfl_xor(inn, 2);
    hr += __shfl_xor(hr, 2); hz += __shfl_xor(hz, 2); hn += __shfl_xor(hn, 2);
  }
  float r = sigf(ir + bih[h] + hr + bhh[h]);
  float z = sigf(iz + bih[256 + h] + hz + bhh[256 + h]);
  float n = tanhfast(inn + bih[512 + h] + r * (hn + bhh[512 + h]));
  float nh = (1.f - z) * n + z * hrw[h];
  if (part == 0) {
    hnew[b * HH + h] = nh;
    sum_out[b * HH + h] = xr[h] + nh;
  }
}

__global__ void __launch_bounds__(256) decoder_kernel(Params p) {
  cg::grid_group grid = cg::this_grid();
  const int gid = blockIdx.x, tid = threadIdx.x;

  // Ph0: zero initial states (d0, g1h0, g2h0)
  for (int i = gid * 256 + tid; i < 3 * 16384; i += 256 * 256) {
    if (i < 16384) p.d0[i] = 0.f;
    else if (i < 32768) p.g1h0[i - 16384] = 0.f;
    else p.g2h0[i - 32768] = 0.f;
  }
  grid.sync();
  // Ph1: d_0 = gru(x_0, 0) -> d1
  if (gid < 128) job_attn_gru(p, 0, p.d0, p.d1, 0);
  grid.sync();
  // Ph2: w2d_0
  if (gid >= 128 && gid < 192) job_w2d(p, p.d1, 128);
  grid.sync();

  const float* dcur = p.d1;
  float* dnxt = p.d0;
  float *g1o = p.g1h0, *g1n = p.g1h1, *g2o = p.g2h0, *g2n = p.g2h1;

  for (int t = 0; t < NSTEP; ++t) {
    // P1: scores(t) || out(t-1)
    if (gid < 128) job_scores(p);
    else if (t > 0) job_out(p, t - 1);
    grid.sync();
    // P2: softmax + context
    job_ctx(p);
    grid.sync();
    // P3: g1in || attn gru d_{t+1}
    if (gid < 128) job_g1in(p, dcur);
    else if (t < NSTEP - 1) job_attn_gru(p, t + 1, dcur, dnxt, 128);
    grid.sync();
    // P4: g1 combine || w2d_{t+1}
    if (gid < 128) job_gru_comb<2>(p.g1in, g1o, p.g1_wih, p.g1_whh, p.g1_bih, p.g1_bhh, g1n, p.g2in);
    else if (gid < 192 && t < NSTEP - 1) job_w2d(p, dnxt, 128);
    grid.sync();
    // P5: g2 combine (all blocks)
    job_gru_comb<4>(p.g2in, g2o, p.g2_wih, p.g2_whh, p.g2_bih, p.g2_bhh, g2n, p.bf);
    grid.sync();
    // swap double buffers
    { const float* tt = dcur; dcur = dnxt; dnxt = (float*)tt; }
    { float* tt = g1o; g1o = g1n; g1n = tt; }
    { float* tt = g2o; g2o = g2n; g2n = tt; }
  }
  // epilogue: out(399)
  if (gid >= 128) job_out(p, NSTEP - 1);
}

extern "C" void kernel_launch(void* const* d_in, const int* in_sizes, int n_in,
                              void* d_out, int out_size, void* d_ws, size_t ws_size,
                              hipStream_t stream) {
  const float* din    = (const float*)d_in[0];
  const float* mem    = (const float*)d_in[1];
  const float* fc1w   = (const float*)d_in[2];
  const float* fc1b   = (const float*)d_in[3];
  const float* fc2w   = (const float*)d_in[4];
  const float* fc2b   = (const float*)d_in[5];
  const float* W1     = (const float*)d_in[6];
  const float* W2     = (const float*)d_in[7];
  const float* vw     = (const float*)d_in[8];
  const float* a_wih  = (const float*)d_in[9];
  const float* a_whh  = (const float*)d_in[10];
  const float* a_bih  = (const float*)d_in[11];
  const float* a_bhh  = (const float*)d_in[12];
  const float* g1_wih = (const float*)d_in[13];
  const float* g1_whh = (const float*)d_in[14];
  const float* g1_bih = (const float*)d_in[15];
  const float* g1_bhh = (const float*)d_in[16];
  const float* g2_wih = (const float*)d_in[17];
  const float* g2_whh = (const float*)d_in[18];
  const float* g2_bih = (const float*)d_in[19];
  const float* g2_bhh = (const float*)d_in[20];
  const float* proj_w = (const float*)d_in[21];
  const float* proj_b = (const float*)d_in[22];
  const float* out_w  = (const float*)d_in[23];
  const float* out_b  = (const float*)d_in[24];

  float* ws = (float*)d_ws;
  size_t o = 0;
  float* tf    = ws + o; o += (size_t)NSTEP * BB * PP;   // 3,276,800
  float* keys  = ws + o; o += (size_t)BB * MM * HH;      // 8,388,608
  float* scr   = ws + o; o += BB * MM;
  float* ctx   = ws + o; o += BB * HH;
  float* d0b   = ws + o; o += BB * HH;
  float* d1b   = ws + o; o += BB * HH;
  float* w2d   = ws + o; o += BB * HH;
  float* g1in  = ws + o; o += BB * HH;
  float* g2in  = ws + o; o += BB * HH;
  float* g1h0  = ws + o; o += BB * HH;
  float* g1h1  = ws + o; o += BB * HH;
  float* g2h0  = ws + o; o += BB * HH;
  float* g2h1  = ws + o; o += BB * HH;
  float* bf    = ws + o; o += BB * HH;

  prenet_kernel<<<dim3(NSTEP, BB), 128, 0, stream>>>(din, fc1w, fc1b, fc2w, fc2b, tf);
  keys_kernel<<<4096, 256, 0, stream>>>(mem, W1, keys);

  Params prm;
  prm.mem = mem; prm.W2 = W2; prm.v = vw;
  prm.a_wih = a_wih; prm.a_whh = a_whh; prm.a_bih = a_bih; prm.a_bhh = a_bhh;
  prm.g1_wih = g1_wih; prm.g1_whh = g1_whh; prm.g1_bih = g1_bih; prm.g1_bhh = g1_bhh;
  prm.g2_wih = g2_wih; prm.g2_whh = g2_whh; prm.g2_bih = g2_bih; prm.g2_bhh = g2_bhh;
  prm.proj_w = proj_w; prm.proj_b = proj_b; prm.out_w = out_w; prm.out_b = out_b;
  prm.tf = tf; prm.keys = keys;
  prm.scores = scr; prm.ctx = ctx; prm.d0 = d0b; prm.d1 = d1b; prm.w2d = w2d;
  prm.g1in = g1in; prm.g2in = g2in; prm.g1h0 = g1h0; prm.g1h1 = g1h1;
  prm.g2h0 = g2h0; prm.g2h1 = g2h1; prm.bf = bf;
  prm.out = (float*)d_out;

  void* args[] = { &prm };
  hipLaunchCooperativeKernel((void*)decoder_kernel, dim3(256), dim3(256), args, 0, stream);
}

// Round 5
// 57191.553 us; speedup vs baseline: 1.8212x; 1.8212x over previous
//
#include <hip/hip_runtime.h>

// Problem constants
constexpr int BB   = 64;     // batch
constexpr int HH   = 256;    // hidden (H)
constexpr int PP   = 128;    // prenet out
constexpr int MM   = 512;    // memory length
constexpr int NM   = 80;     // num mels
constexpr int RR   = 5;      // outputs per step
constexpr int TIN  = 2000;   // input time
constexpr int NSTEP= 400;    // decoder steps

__device__ __forceinline__ float sigf(float x)  { return 1.0f / (1.0f + __expf(-x)); }
__device__ __forceinline__ float tanhfast(float x) { return 1.0f - 2.0f / (1.0f + __expf(2.0f * x)); }
__device__ __forceinline__ unsigned short bf16rne(float x) {
  unsigned int u = __float_as_uint(x);
  u += 0x7fffu + ((u >> 16) & 1u);
  return (unsigned short)(u >> 16);
}

// ---------------- prenet: only the 400 consumed frames ----------------
__global__ void __launch_bounds__(128) prenet_kernel(
    const float* __restrict__ din, const float* __restrict__ fc1w, const float* __restrict__ fc1b,
    const float* __restrict__ fc2w, const float* __restrict__ fc2b, float* __restrict__ tf) {
  int t = blockIdx.x, b = blockIdx.y, tid = threadIdx.x;
  __shared__ float x[NM];
  __shared__ float h1[256];
  if (tid < NM) x[tid] = din[(size_t)b * NM * TIN + (size_t)tid * TIN + t * RR];
  __syncthreads();
  for (int o = tid; o < 256; o += 128) {
    float a = fc1b[o];
    const float* w = fc1w + o * NM;
    for (int k = 0; k < NM; ++k) a += x[k] * w[k];
    h1[o] = fmaxf(a, 0.f);
  }
  __syncthreads();
  {
    int o = tid;
    float a = fc2b[o];
    const float* w = fc2w + o * 256;
    for (int k = 0; k < 256; ++k) a += h1[k] * w[k];
    tf[((size_t)t * BB + b) * PP + o] = fmaxf(a, 0.f);
  }
}

// ---------------- generic fp32 transpose: src (R x C) -> dst (C x R) ----------------
__global__ void __launch_bounds__(256) transpose_kernel(
    const float* __restrict__ src, float* __restrict__ dst, int R, int C) {
  __shared__ float tile[32][33];
  int tx = threadIdx.x, ty = threadIdx.y;
  int c0 = blockIdx.x * 32, r0 = blockIdx.y * 32;
  for (int i = 0; i < 32; i += 8) {
    int r = r0 + ty + i;
    if (r < R && c0 + tx < C) tile[ty + i][tx] = src[(size_t)r * C + c0 + tx];
  }
  __syncthreads();
  for (int i = 0; i < 32; i += 8) {
    int c = c0 + ty + i;
    if (c < C && r0 + tx < R) dst[(size_t)c * R + r0 + tx] = tile[tx][ty + i];
  }
}

// ---------------- keysT = bf16( (memory @ W1^T)^T per b ) : [b][h][m] ----------------
__global__ void __launch_bounds__(256) keysT_kernel(
    const float* __restrict__ mem, const float* __restrict__ W1, unsigned short* __restrict__ keysT) {
  int blk = blockIdx.x;
  int b = blk >> 6, mc = blk & 63, m0 = mc * 8, tid = threadIdx.x;
  __shared__ float sm[8 * 256];
  for (int i = tid; i < 2048; i += 256)
    sm[i] = mem[((size_t)b * MM + m0 + (i >> 8)) * HH + (i & 255)];
  __syncthreads();
  float acc[8] = {0, 0, 0, 0, 0, 0, 0, 0};
  const float* w = W1 + (size_t)tid * 256;
  for (int k = 0; k < 256; ++k) {
    float wk = w[k];
#pragma unroll
    for (int r = 0; r < 8; ++r) acc[r] += sm[r * 256 + k] * wk;
  }
  // thread tid holds keys[b][m0+r][tid] = keysT[b][tid][m0+r] for r in [0,8)
  size_t base = ((size_t)b * HH + tid) * MM + m0;
#pragma unroll
  for (int r = 0; r < 8; ++r) keysT[base + r] = bf16rne(acc[r]);
}

// ---------------- the per-batch-element decoder: 1 block = 1 b, no grid syncs ----------------
struct DP {
  const float *mem, *tf;
  const float *W2T, *projT, *outWT;
  const float *awihT, *awhhT, *g1wihT, *g1whhT, *g2wihT, *g2whhT;
  const float *a_bih, *a_bhh, *g1_bih, *g1_bhh, *g2_bih, *g2_bhh;
  const float *proj_b, *out_b, *v;
  const unsigned short *keysT;
  float *out;
};

// bias LDS layout offsets
//   0    a_bih[768]   768  a_bhh[768]
//   1536 g1_bih[768]  2304 g1_bhh[768]
//   3072 g2_bih[768]  3840 g2_bhh[768]
//   4608 proj_b[256]  4864 out_b[400]  5264 v[256]   total 5520
__global__ void __launch_bounds__(1024) decoder64(DP p) {
  const int b = blockIdx.x, tid = threadIdx.x;
  const int lane = tid & 63, wid = tid >> 6;
  __shared__ float d_s[256], xf[128], w2dv[256], sc[512], ctxv[256];
  __shared__ float g1inv[256], g2inv[256], g1h[256], g2h[256], bfv[256];
  __shared__ float gbuf[1536], red[1024], wredA[16], wredB[16];
  __shared__ float bias[5520];

  if (tid < 768) {
    bias[tid]        = p.a_bih[tid];  bias[768 + tid]  = p.a_bhh[tid];
    bias[1536 + tid] = p.g1_bih[tid]; bias[2304 + tid] = p.g1_bhh[tid];
    bias[3072 + tid] = p.g2_bih[tid]; bias[3840 + tid] = p.g2_bhh[tid];
  }
  if (tid < 256) { bias[4608 + tid] = p.proj_b[tid]; bias[5264 + tid] = p.v[tid]; }
  if (tid < 400) bias[4864 + tid] = p.out_b[tid];
  if (tid < 256) { d_s[tid] = 0.f; g1h[tid] = 0.f; g2h[tid] = 0.f; }
  __syncthreads();

  for (int t = 0; t < NSTEP; ++t) {
    // --- Phase A: attention GRU  d = GRU(x_t, d) ---
    if (tid < 128) xf[tid] = p.tf[((size_t)t * BB + b) * PP + tid];
    __syncthreads();
    if (tid < 768) {
      float acc = 0.f, acc2 = 0.f;
      const float* w = p.awihT + tid;
      const float* u = p.awhhT + tid;
#pragma unroll 4
      for (int k = 0; k < 128; ++k) acc += w[(size_t)k * 768] * xf[k];
#pragma unroll 4
      for (int k = 0; k < 256; ++k) acc2 += u[(size_t)k * 768] * d_s[k];
      gbuf[tid] = acc; gbuf[768 + tid] = acc2;
    }
    __syncthreads();
    if (tid < 256) {
      int h = tid;
      float r = sigf(gbuf[h]       + bias[h]       + gbuf[768 + h]  + bias[768 + h]);
      float z = sigf(gbuf[256 + h] + bias[256 + h] + gbuf[1024 + h] + bias[1024 + h]);
      float n = tanhfast(gbuf[512 + h] + bias[512 + h] + r * (gbuf[1280 + h] + bias[1280 + h]));
      d_s[h] = (1.f - z) * n + z * d_s[h];
    }
    __syncthreads();

    // --- Phase B: w2d = W2 @ d ---
    {
      int o = tid & 255, kp = tid >> 8;
      const float* w = p.W2T + (size_t)(kp * 64) * 256 + o;
      float acc = 0.f;
#pragma unroll 4
      for (int k = 0; k < 64; ++k) acc += w[(size_t)k * 256] * d_s[kp * 64 + k];
      red[tid] = acc;
    }
    __syncthreads();
    if (tid < 256) w2dv[tid] = red[tid] + red[256 + tid] + red[512 + tid] + red[768 + tid];
    __syncthreads();

    // --- Phase C: scores[m] = sum_h v[h] * tanh(keysT[b][h][m] + w2d[h]) ---
    {
      int m = tid & 511, kp = tid >> 9;
      const unsigned short* kq = p.keysT + ((size_t)b * HH + kp * 128) * MM + m;
      float acc = 0.f;
#pragma unroll 2
      for (int h = 0; h < 128; ++h) {
        float key = __uint_as_float(((unsigned int)kq[(size_t)h * MM]) << 16);
        float x = key + w2dv[kp * 128 + h];
        acc += bias[5264 + kp * 128 + h] * tanhfast(x);
      }
      red[tid] = acc;
    }
    __syncthreads();
    if (tid < 512) sc[tid] = red[tid] + red[512 + tid];
    __syncthreads();

    // --- Phase D: softmax over 512 (wave shuffles + tiny LDS tree) ---
    {
      float s = (tid < 512) ? sc[tid] : -1e30f;
      float mx = s;
      for (int off = 32; off; off >>= 1) mx = fmaxf(mx, __shfl_xor(mx, off));
      if (lane == 0) wredA[wid] = mx;
      __syncthreads();
      float gmax = wredA[0];
      for (int i = 1; i < 16; ++i) gmax = fmaxf(gmax, wredA[i]);
      float e = (tid < 512) ? __expf(s - gmax) : 0.f;
      float sum = e;
      for (int off = 32; off; off >>= 1) sum += __shfl_xor(sum, off);
      if (lane == 0) wredB[wid] = sum;
      __syncthreads();
      float gsum = 0.f;
      for (int i = 0; i < 16; ++i) gsum += wredB[i];
      if (tid < 512) sc[tid] = e / gsum;
    }
    __syncthreads();

    // --- Phase E: ctx[h] = sum_m attw[m] * mem[b][m][h] ---
    {
      int o = tid & 255, mp = tid >> 8;
      const float* mb = p.mem + ((size_t)b * MM + mp * 128) * HH + o;
      float acc = 0.f;
#pragma unroll 4
      for (int m = 0; m < 128; ++m) acc += sc[mp * 128 + m] * mb[(size_t)m * HH];
      red[tid] = acc;
    }
    __syncthreads();
    if (tid < 256) ctxv[tid] = red[tid] + red[256 + tid] + red[512 + tid] + red[768 + tid];
    __syncthreads();

    // --- Phase F: g1in = proj @ concat(d, ctx) + proj_b ---
    {
      int o = tid & 255, kp = tid >> 8;
      const float* w = p.projT + (size_t)(kp * 128) * 256 + o;
      const float* u = (kp < 2) ? d_s : ctxv;
      int k0 = (kp & 1) * 128;
      float acc = 0.f;
#pragma unroll 4
      for (int k = 0; k < 128; ++k) acc += w[(size_t)k * 256] * u[k0 + k];
      red[tid] = acc;
    }
    __syncthreads();
    if (tid < 256) g1inv[tid] = red[tid] + red[256 + tid] + red[512 + tid] + red[768 + tid] + bias[4608 + tid];
    __syncthreads();

    // --- Phase G: GRU1; g2in = g1in + g1h ---
    if (tid < 768) {
      float acc = 0.f, acc2 = 0.f;
      const float* w = p.g1wihT + tid;
      const float* u = p.g1whhT + tid;
#pragma unroll 4
      for (int k = 0; k < 256; ++k) { acc += w[(size_t)k * 768] * g1inv[k]; acc2 += u[(size_t)k * 768] * g1h[k]; }
      gbuf[tid] = acc; gbuf[768 + tid] = acc2;
    }
    __syncthreads();
    if (tid < 256) {
      int h = tid;
      float r = sigf(gbuf[h]       + bias[1536 + h] + gbuf[768 + h]  + bias[2304 + h]);
      float z = sigf(gbuf[256 + h] + bias[1792 + h] + gbuf[1024 + h] + bias[2560 + h]);
      float n = tanhfast(gbuf[512 + h] + bias[2048 + h] + r * (gbuf[1280 + h] + bias[2816 + h]));
      float nh = (1.f - z) * n + z * g1h[h];
      g1h[h] = nh;
      g2inv[h] = g1inv[h] + nh;
    }
    __syncthreads();

    // --- Phase H: GRU2; bf = g2in + g2h ---
    if (tid < 768) {
      float acc = 0.f, acc2 = 0.f;
      const float* w = p.g2wihT + tid;
      const float* u = p.g2whhT + tid;
#pragma unroll 4
      for (int k = 0; k < 256; ++k) { acc += w[(size_t)k * 768] * g2inv[k]; acc2 += u[(size_t)k * 768] * g2h[k]; }
      gbuf[tid] = acc; gbuf[768 + tid] = acc2;
    }
    __syncthreads();
    if (tid < 256) {
      int h = tid;
      float r = sigf(gbuf[h]       + bias[3072 + h] + gbuf[768 + h]  + bias[3840 + h]);
      float z = sigf(gbuf[256 + h] + bias[3328 + h] + gbuf[1024 + h] + bias[4096 + h]);
      float n = tanhfast(gbuf[512 + h] + bias[3584 + h] + r * (gbuf[1280 + h] + bias[4352 + h]));
      float nh = (1.f - z) * n + z * g2h[h];
      g2h[h] = nh;
      bfv[h] = g2inv[h] + nh;
    }
    __syncthreads();

    // --- Phase I: out = out_w @ bf + out_b ---
    if (tid < 800) {
      int j  = (tid < 400) ? tid : tid - 400;
      int kp = (tid < 400) ? 0 : 1;
      const float* w = p.outWT + (size_t)(kp * 128) * 400 + j;
      float acc = 0.f;
#pragma unroll 4
      for (int k = 0; k < 128; ++k) acc += w[(size_t)k * 400] * bfv[kp * 128 + k];
      red[tid] = acc;
    }
    __syncthreads();
    if (tid < 400) {
      float a = red[tid] + red[400 + tid] + bias[4864 + tid];
      int mel = tid / 5, r = tid - mel * 5;
      p.out[(size_t)b * NM * TIN + (size_t)mel * TIN + t * RR + r] = a;
    }
    __syncthreads();
  }
}

extern "C" void kernel_launch(void* const* d_in, const int* in_sizes, int n_in,
                              void* d_out, int out_size, void* d_ws, size_t ws_size,
                              hipStream_t stream) {
  const float* din    = (const float*)d_in[0];
  const float* mem    = (const float*)d_in[1];
  const float* fc1w   = (const float*)d_in[2];
  const float* fc1b   = (const float*)d_in[3];
  const float* fc2w   = (const float*)d_in[4];
  const float* fc2b   = (const float*)d_in[5];
  const float* W1     = (const float*)d_in[6];
  const float* W2     = (const float*)d_in[7];
  const float* vw     = (const float*)d_in[8];
  const float* a_wih  = (const float*)d_in[9];
  const float* a_whh  = (const float*)d_in[10];
  const float* a_bih  = (const float*)d_in[11];
  const float* a_bhh  = (const float*)d_in[12];
  const float* g1_wih = (const float*)d_in[13];
  const float* g1_whh = (const float*)d_in[14];
  const float* g1_bih = (const float*)d_in[15];
  const float* g1_bhh = (const float*)d_in[16];
  const float* g2_wih = (const float*)d_in[17];
  const float* g2_whh = (const float*)d_in[18];
  const float* g2_bih = (const float*)d_in[19];
  const float* g2_bhh = (const float*)d_in[20];
  const float* proj_w = (const float*)d_in[21];
  const float* proj_b = (const float*)d_in[22];
  const float* out_w  = (const float*)d_in[23];
  const float* out_b  = (const float*)d_in[24];

  float* ws = (float*)d_ws;
  size_t o = 0;
  float* tf     = ws + o; o += (size_t)NSTEP * BB * PP;  // 3,276,800
  float* W2T    = ws + o; o += 256 * 256;
  float* projT  = ws + o; o += 512 * 256;
  float* outWT  = ws + o; o += 256 * 400;
  float* awihT  = ws + o; o += 128 * 768;
  float* awhhT  = ws + o; o += 256 * 768;
  float* g1wihT = ws + o; o += 256 * 768;
  float* g1whhT = ws + o; o += 256 * 768;
  float* g2wihT = ws + o; o += 256 * 768;
  float* g2whhT = ws + o; o += 256 * 768;
  unsigned short* keysT = (unsigned short*)(ws + o); o += (size_t)BB * HH * MM / 2;  // bf16

  prenet_kernel<<<dim3(NSTEP, BB), 128, 0, stream>>>(din, fc1w, fc1b, fc2w, fc2b, tf);

  dim3 tb(32, 8);
  transpose_kernel<<<dim3(256 / 32, 256 / 32), tb, 0, stream>>>(W2,     W2T,    256, 256);
  transpose_kernel<<<dim3(512 / 32, 256 / 32), tb, 0, stream>>>(proj_w, projT,  256, 512);
  transpose_kernel<<<dim3(256 / 32, (400 + 31) / 32), tb, 0, stream>>>(out_w, outWT, 400, 256);
  transpose_kernel<<<dim3(128 / 32, 768 / 32), tb, 0, stream>>>(a_wih,  awihT,  768, 128);
  transpose_kernel<<<dim3(256 / 32, 768 / 32), tb, 0, stream>>>(a_whh,  awhhT,  768, 256);
  transpose_kernel<<<dim3(256 / 32, 768 / 32), tb, 0, stream>>>(g1_wih, g1wihT, 768, 256);
  transpose_kernel<<<dim3(256 / 32, 768 / 32), tb, 0, stream>>>(g1_whh, g1whhT, 768, 256);
  transpose_kernel<<<dim3(256 / 32, 768 / 32), tb, 0, stream>>>(g2_wih, g2wihT, 768, 256);
  transpose_kernel<<<dim3(256 / 32, 768 / 32), tb, 0, stream>>>(g2_whh, g2whhT, 768, 256);

  keysT_kernel<<<4096, 256, 0, stream>>>(mem, W1, keysT);

  DP p;
  p.mem = mem; p.tf = tf;
  p.W2T = W2T; p.projT = projT; p.outWT = outWT;
  p.awihT = awihT; p.awhhT = awhhT;
  p.g1wihT = g1wihT; p.g1whhT = g1whhT; p.g2wihT = g2wihT; p.g2whhT = g2whhT;
  p.a_bih = a_bih; p.a_bhh = a_bhh; p.g1_bih = g1_bih; p.g1_bhh = g1_bhh;
  p.g2_bih = g2_bih; p.g2_bhh = g2_bhh;
  p.proj_b = proj_b; p.out_b = out_b; p.v = vw;
  p.keysT = keysT;
  p.out = (float*)d_out;

  decoder64<<<BB, 1024, 0, stream>>>(p);
}

// Round 6
// 25362.759 us; speedup vs baseline: 4.1066x; 2.2549x over previous
//
#include <hip/hip_runtime.h>

// Problem constants
constexpr int BB   = 64;     // batch
constexpr int HH   = 256;    // hidden (H)
constexpr int PP   = 128;    // prenet out
constexpr int MM   = 512;    // memory length
constexpr int NM   = 80;     // num mels
constexpr int RR   = 5;      // outputs per step
constexpr int TIN  = 2000;   // input time
constexpr int NSTEP= 400;    // decoder steps

__device__ __forceinline__ float sigf(float x)  { return 1.0f / (1.0f + __expf(-x)); }
__device__ __forceinline__ float tanhfast(float x) { return 1.0f - 2.0f / (1.0f + __expf(2.0f * x)); }
__device__ __forceinline__ unsigned short bf16rne(float x) {
  unsigned int u = __float_as_uint(x);
  u += 0x7fffu + ((u >> 16) & 1u);
  return (unsigned short)(u >> 16);
}
__device__ __forceinline__ unsigned packbf(float a, float b) {
  return (unsigned)bf16rne(a) | ((unsigned)bf16rne(b) << 16);
}
// u = pack(v0, v1): .x = v0, .y = v1
__device__ __forceinline__ float2 unpk(unsigned u) {
  float2 r;
  r.x = __uint_as_float(u << 16);
  r.y = __uint_as_float(u & 0xffff0000u);
  return r;
}

// ---------------- prenet: only the 400 consumed frames ----------------
__global__ void __launch_bounds__(128) prenet_kernel(
    const float* __restrict__ din, const float* __restrict__ fc1w, const float* __restrict__ fc1b,
    const float* __restrict__ fc2w, const float* __restrict__ fc2b, float* __restrict__ tf) {
  int t = blockIdx.x, b = blockIdx.y, tid = threadIdx.x;
  __shared__ float x[NM];
  __shared__ float h1[256];
  if (tid < NM) x[tid] = din[(size_t)b * NM * TIN + (size_t)tid * TIN + t * RR];
  __syncthreads();
  for (int o = tid; o < 256; o += 128) {
    float a = fc1b[o];
    const float* w = fc1w + o * NM;
    for (int k = 0; k < NM; ++k) a += x[k] * w[k];
    h1[o] = fmaxf(a, 0.f);
  }
  __syncthreads();
  {
    int o = tid;
    float a = fc2b[o];
    const float* w = fc2w + o * 256;
    for (int k = 0; k < 256; ++k) a += h1[k] * w[k];
    tf[((size_t)t * BB + b) * PP + o] = fmaxf(a, 0.f);
  }
}

// ---------------- pack+transpose: src fp32 [O][K] -> dst uint [K/2][O], pair (2k,2k+1) ----------------
__global__ void __launch_bounds__(256) packT_kernel(
    const float* __restrict__ src, unsigned* __restrict__ dst, int O, int K) {
  int K2 = K >> 1;
  int idx = blockIdx.x * 256 + threadIdx.x;
  if (idx >= O * K2) return;
  int k2 = idx % K2, o = idx / K2;
  float a = src[(size_t)o * K + 2 * k2];
  float b = src[(size_t)o * K + 2 * k2 + 1];
  dst[(size_t)k2 * O + o] = packbf(a, b);
}

// ---------------- memB2: mem fp32 [b][m][h] -> uint [b][m][h/2] ----------------
__global__ void __launch_bounds__(256) packMem_kernel(
    const float* __restrict__ mem, unsigned* __restrict__ memB2) {
  int idx = blockIdx.x * 256 + threadIdx.x;   // over BB*MM*128
  if (idx >= BB * MM * 128) return;
  memB2[idx] = packbf(mem[2 * (size_t)idx], mem[2 * (size_t)idx + 1]);
}

// ---------------- key2 = packed bf16 keys: uint [b][h/2][m] (pair h=2hp, 2hp+1) ----------------
__global__ void __launch_bounds__(256) keys2_kernel(
    const float* __restrict__ mem, const float* __restrict__ W1, unsigned* __restrict__ key2) {
  int blk = blockIdx.x;
  int b = blk >> 6, mc = blk & 63, m0 = mc * 8, tid = threadIdx.x;
  __shared__ float sm[2048];
  for (int i = tid; i < 2048; i += 256)
    sm[i] = mem[((size_t)b * MM + m0 + (i >> 8)) * HH + (i & 255)];
  __syncthreads();
  float acc[8] = {0, 0, 0, 0, 0, 0, 0, 0};
  const float* w = W1 + (size_t)tid * 256;
  for (int k = 0; k < 256; ++k) {
    float wk = w[k];
#pragma unroll
    for (int r = 0; r < 8; ++r) acc[r] += sm[r * 256 + k] * wk;
  }
  __syncthreads();   // all reads of sm done
#pragma unroll
  for (int r = 0; r < 8; ++r) sm[tid * 8 + r] = acc[r];   // sm[h][r], h = tid
  __syncthreads();
#pragma unroll
  for (int j = 0; j < 4; ++j) {
    int slot = tid * 4 + j;          // [0,1024): 128 hp x 8 r
    int hp = slot >> 3, r = slot & 7;
    float lo = sm[(2 * hp) * 8 + r], hi = sm[(2 * hp + 1) * 8 + r];
    key2[((size_t)b * 128 + hp) * MM + m0 + r] = packbf(lo, hi);
  }
}

// ---------------- the per-batch-element decoder: 1 block = 1 b ----------------
struct DP {
  const float *tf;
  const unsigned *W2P, *projP, *outP;
  const unsigned *awihP, *awhhP, *g1wihP, *g1whhP, *g2wihP, *g2whhP;
  const unsigned *key2, *memB2;
  const float *a_bih, *a_bhh, *g1_bih, *g1_bhh, *g2_bih, *g2_bhh;
  const float *proj_b, *out_b, *v;
  float *out;
};

// bias LDS layout offsets
//   0    a_bih[768]   768  a_bhh[768]
//   1536 g1_bih[768]  2304 g1_bhh[768]
//   3072 g2_bih[768]  3840 g2_bhh[768]
//   4608 proj_b[256]  4864 out_b[400]  5264 v[256]   total 5520
__global__ void __launch_bounds__(1024) decoder64(DP p) {
  const int b = blockIdx.x, tid = threadIdx.x;
  const int lane = tid & 63, wid = tid >> 6;
  __shared__ float d_s[256], xf[128], w2dv[256], sc[512], ctxv[256];
  __shared__ float g1inv[256], g2inv[256], g1h[256], g2h[256], bfv[256];
  __shared__ float gbuf[1536], red[2048], wredA[16], wredB[16];
  __shared__ float bias[5520];

  if (tid < 768) {
    bias[tid]        = p.a_bih[tid];  bias[768 + tid]  = p.a_bhh[tid];
    bias[1536 + tid] = p.g1_bih[tid]; bias[2304 + tid] = p.g1_bhh[tid];
    bias[3072 + tid] = p.g2_bih[tid]; bias[3840 + tid] = p.g2_bhh[tid];
  }
  if (tid < 256) { bias[4608 + tid] = p.proj_b[tid]; bias[5264 + tid] = p.v[tid]; }
  if (tid < 400) bias[4864 + tid] = p.out_b[tid];
  if (tid < 256) { d_s[tid] = 0.f; g1h[tid] = 0.f; g2h[tid] = 0.f; }
  __syncthreads();

  for (int t = 0; t < NSTEP; ++t) {
    // --- Phase A: attention GRU  d = GRU(x_t, d) ---
    if (tid < 128) xf[tid] = p.tf[((size_t)t * BB + b) * PP + tid];
    __syncthreads();
    if (tid < 768) {
      float acc = 0.f, acc2 = 0.f;
      const unsigned* w = p.awihP + tid;   // [64][768]
      const unsigned* u = p.awhhP + tid;   // [128][768]
#pragma unroll 8
      for (int kk = 0; kk < 64; ++kk) {
        float2 f = unpk(w[(size_t)kk * 768]);
        acc += f.x * xf[2 * kk] + f.y * xf[2 * kk + 1];
      }
#pragma unroll 8
      for (int kk = 0; kk < 128; ++kk) {
        float2 f = unpk(u[(size_t)kk * 768]);
        acc2 += f.x * d_s[2 * kk] + f.y * d_s[2 * kk + 1];
      }
      gbuf[tid] = acc; gbuf[768 + tid] = acc2;
    }
    __syncthreads();
    if (tid < 256) {
      int h = tid;
      float r = sigf(gbuf[h]       + bias[h]       + gbuf[768 + h]  + bias[768 + h]);
      float z = sigf(gbuf[256 + h] + bias[256 + h] + gbuf[1024 + h] + bias[1024 + h]);
      float n = tanhfast(gbuf[512 + h] + bias[512 + h] + r * (gbuf[1280 + h] + bias[1280 + h]));
      d_s[h] = (1.f - z) * n + z * d_s[h];
    }
    __syncthreads();

    // --- Phase B: w2d = W2 @ d   (W2P uint [128][256], kp in [0,4) covers k2 32 each) ---
    {
      int o = tid & 255, kp = tid >> 8;
      const unsigned* w = p.W2P + (size_t)(kp * 32) * 256 + o;
      float acc = 0.f;
#pragma unroll 8
      for (int kk = 0; kk < 32; ++kk) {
        float2 f = unpk(w[(size_t)kk * 256]);
        acc += f.x * d_s[kp * 64 + 2 * kk] + f.y * d_s[kp * 64 + 2 * kk + 1];
      }
      red[tid] = acc;
    }
    __syncthreads();
    if (tid < 256) w2dv[tid] = red[tid] + red[256 + tid] + red[512 + tid] + red[768 + tid];
    __syncthreads();

    // --- Phase C: scores[m] = sum_h v[h] * tanh(keys[b][h][m] + w2d[h]), packed h-pairs ---
    {
      int m = tid & 511, kp = tid >> 9;   // kp in {0,1}: hp halves
      const unsigned* kq = p.key2 + ((size_t)b * 128 + kp * 64) * MM + m;
      float acc = 0.f;
#pragma unroll 4
      for (int i = 0; i < 64; ++i) {
        float2 f = unpk(kq[(size_t)i * MM]);
        int h0 = (kp * 64 + i) * 2;
        acc += bias[5264 + h0]     * tanhfast(f.x + w2dv[h0]);
        acc += bias[5264 + h0 + 1] * tanhfast(f.y + w2dv[h0 + 1]);
      }
      red[tid] = acc;
    }
    __syncthreads();
    if (tid < 512) sc[tid] = red[tid] + red[512 + tid];
    __syncthreads();

    // --- Phase D: softmax over 512 ---
    {
      float s = (tid < 512) ? sc[tid] : -1e30f;
      float mx = s;
      for (int off = 32; off; off >>= 1) mx = fmaxf(mx, __shfl_xor(mx, off));
      if (lane == 0) wredA[wid] = mx;
      __syncthreads();
      float gmax = wredA[0];
      for (int i = 1; i < 16; ++i) gmax = fmaxf(gmax, wredA[i]);
      float e = (tid < 512) ? __expf(s - gmax) : 0.f;
      float sum = e;
      for (int off = 32; off; off >>= 1) sum += __shfl_xor(sum, off);
      if (lane == 0) wredB[wid] = sum;
      __syncthreads();
      float gsum = 0.f;
      for (int i = 0; i < 16; ++i) gsum += wredB[i];
      if (tid < 512) sc[tid] = e / gsum;
    }
    __syncthreads();

    // --- Phase E: ctx[h] = sum_m attw[m] * mem[b][m][h]  (memB2 uint [b][m][128], h-pairs) ---
    {
      int hp = tid & 127, mp = tid >> 7;   // mp in [0,8): 64 m each
      const unsigned* mb = p.memB2 + ((size_t)b * MM + mp * 64) * 128 + hp;
      float acc0 = 0.f, acc1 = 0.f;
#pragma unroll 8
      for (int m = 0; m < 64; ++m) {
        float2 f = unpk(mb[(size_t)m * 128]);
        float wgt = sc[mp * 64 + m];
        acc0 += wgt * f.x; acc1 += wgt * f.y;
      }
      red[mp * 256 + 2 * hp] = acc0;
      red[mp * 256 + 2 * hp + 1] = acc1;
    }
    __syncthreads();
    if (tid < 256) {
      float a = 0.f;
#pragma unroll
      for (int mp = 0; mp < 8; ++mp) a += red[mp * 256 + tid];
      ctxv[tid] = a;
    }
    __syncthreads();

    // --- Phase F: g1in = proj @ concat(d, ctx) + proj_b  (projP uint [256][256]) ---
    {
      int o = tid & 255, q = tid >> 8;    // q in [0,4): k-quarters of 128
      const unsigned* w = p.projP + (size_t)(q * 64) * 256 + o;
      const float* u = (q < 2) ? d_s : ctxv;
      int k0 = (q & 1) * 128;
      float acc = 0.f;
#pragma unroll 8
      for (int kk = 0; kk < 64; ++kk) {
        float2 f = unpk(w[(size_t)kk * 256]);
        acc += f.x * u[k0 + 2 * kk] + f.y * u[k0 + 2 * kk + 1];
      }
      red[tid] = acc;
    }
    __syncthreads();
    if (tid < 256) g1inv[tid] = red[tid] + red[256 + tid] + red[512 + tid] + red[768 + tid] + bias[4608 + tid];
    __syncthreads();

    // --- Phase G: GRU1; g2in = g1in + g1h  (g1wihP/g1whhP uint [128][768]) ---
    if (tid < 768) {
      float acc = 0.f, acc2 = 0.f;
      const unsigned* w = p.g1wihP + tid;
      const unsigned* u = p.g1whhP + tid;
#pragma unroll 8
      for (int kk = 0; kk < 128; ++kk) {
        float2 fw = unpk(w[(size_t)kk * 768]);
        float2 fu = unpk(u[(size_t)kk * 768]);
        acc  += fw.x * g1inv[2 * kk] + fw.y * g1inv[2 * kk + 1];
        acc2 += fu.x * g1h[2 * kk]   + fu.y * g1h[2 * kk + 1];
      }
      gbuf[tid] = acc; gbuf[768 + tid] = acc2;
    }
    __syncthreads();
    if (tid < 256) {
      int h = tid;
      float r = sigf(gbuf[h]       + bias[1536 + h] + gbuf[768 + h]  + bias[2304 + h]);
      float z = sigf(gbuf[256 + h] + bias[1792 + h] + gbuf[1024 + h] + bias[2560 + h]);
      float n = tanhfast(gbuf[512 + h] + bias[2048 + h] + r * (gbuf[1280 + h] + bias[2816 + h]));
      float nh = (1.f - z) * n + z * g1h[h];
      g1h[h] = nh;
      g2inv[h] = g1inv[h] + nh;
    }
    __syncthreads();

    // --- Phase H: GRU2; bf = g2in + g2h ---
    if (tid < 768) {
      float acc = 0.f, acc2 = 0.f;
      const unsigned* w = p.g2wihP + tid;
      const unsigned* u = p.g2whhP + tid;
#pragma unroll 8
      for (int kk = 0; kk < 128; ++kk) {
        float2 fw = unpk(w[(size_t)kk * 768]);
        float2 fu = unpk(u[(size_t)kk * 768]);
        acc  += fw.x * g2inv[2 * kk] + fw.y * g2inv[2 * kk + 1];
        acc2 += fu.x * g2h[2 * kk]   + fu.y * g2h[2 * kk + 1];
      }
      gbuf[tid] = acc; gbuf[768 + tid] = acc2;
    }
    __syncthreads();
    if (tid < 256) {
      int h = tid;
      float r = sigf(gbuf[h]       + bias[3072 + h] + gbuf[768 + h]  + bias[3840 + h]);
      float z = sigf(gbuf[256 + h] + bias[3328 + h] + gbuf[1024 + h] + bias[4096 + h]);
      float n = tanhfast(gbuf[512 + h] + bias[3584 + h] + r * (gbuf[1280 + h] + bias[4352 + h]));
      float nh = (1.f - z) * n + z * g2h[h];
      g2h[h] = nh;
      bfv[h] = g2inv[h] + nh;
    }
    __syncthreads();

    // --- Phase I: out = out_w @ bf + out_b  (outP uint [128][400]) ---
    if (tid < 800) {
      int j  = (tid < 400) ? tid : tid - 400;
      int kp = (tid < 400) ? 0 : 1;
      const unsigned* w = p.outP + (size_t)(kp * 64) * 400 + j;
      float acc = 0.f;
#pragma unroll 8
      for (int kk = 0; kk < 64; ++kk) {
        float2 f = unpk(w[(size_t)kk * 400]);
        acc += f.x * bfv[kp * 128 + 2 * kk] + f.y * bfv[kp * 128 + 2 * kk + 1];
      }
      red[tid] = acc;
    }
    __syncthreads();
    if (tid < 400) {
      float a = red[tid] + red[400 + tid] + bias[4864 + tid];
      int mel = tid / 5, r = tid - mel * 5;
      p.out[(size_t)b * NM * TIN + (size_t)mel * TIN + t * RR + r] = a;
    }
    __syncthreads();
  }
}

extern "C" void kernel_launch(void* const* d_in, const int* in_sizes, int n_in,
                              void* d_out, int out_size, void* d_ws, size_t ws_size,
                              hipStream_t stream) {
  const float* din    = (const float*)d_in[0];
  const float* mem    = (const float*)d_in[1];
  const float* fc1w   = (const float*)d_in[2];
  const float* fc1b   = (const float*)d_in[3];
  const float* fc2w   = (const float*)d_in[4];
  const float* fc2b   = (const float*)d_in[5];
  const float* W1     = (const float*)d_in[6];
  const float* W2     = (const float*)d_in[7];
  const float* vw     = (const float*)d_in[8];
  const float* a_wih  = (const float*)d_in[9];
  const float* a_whh  = (const float*)d_in[10];
  const float* a_bih  = (const float*)d_in[11];
  const float* a_bhh  = (const float*)d_in[12];
  const float* g1_wih = (const float*)d_in[13];
  const float* g1_whh = (const float*)d_in[14];
  const float* g1_bih = (const float*)d_in[15];
  const float* g1_bhh = (const float*)d_in[16];
  const float* g2_wih = (const float*)d_in[17];
  const float* g2_whh = (const float*)d_in[18];
  const float* g2_bih = (const float*)d_in[19];
  const float* g2_bhh = (const float*)d_in[20];
  const float* proj_w = (const float*)d_in[21];
  const float* proj_b = (const float*)d_in[22];
  const float* out_w  = (const float*)d_in[23];
  const float* out_b  = (const float*)d_in[24];

  float* ws = (float*)d_ws;
  size_t o = 0;
  float* tf = ws + o;               o += (size_t)NSTEP * BB * PP;       // 3,276,800 f
  unsigned* W2P    = (unsigned*)(ws + o); o += 128 * 256;               // k2 x O
  unsigned* projP  = (unsigned*)(ws + o); o += 256 * 256;
  unsigned* outP   = (unsigned*)(ws + o); o += 128 * 400;
  unsigned* awihP  = (unsigned*)(ws + o); o += 64 * 768;
  unsigned* awhhP  = (unsigned*)(ws + o); o += 128 * 768;
  unsigned* g1wihP = (unsigned*)(ws + o); o += 128 * 768;
  unsigned* g1whhP = (unsigned*)(ws + o); o += 128 * 768;
  unsigned* g2wihP = (unsigned*)(ws + o); o += 128 * 768;
  unsigned* g2whhP = (unsigned*)(ws + o); o += 128 * 768;
  unsigned* key2   = (unsigned*)(ws + o); o += (size_t)BB * 128 * MM;   // 4,194,304 u
  unsigned* memB2  = (unsigned*)(ws + o); o += (size_t)BB * MM * 128;   // 4,194,304 u

  prenet_kernel<<<dim3(NSTEP, BB), 128, 0, stream>>>(din, fc1w, fc1b, fc2w, fc2b, tf);

  auto packT = [&](const float* src, unsigned* dst, int O, int K) {
    int n = O * (K / 2);
    packT_kernel<<<(n + 255) / 256, 256, 0, stream>>>(src, dst, O, K);
  };
  packT(W2,     W2P,    256, 256);
  packT(proj_w, projP,  256, 512);
  packT(out_w,  outP,   400, 256);
  packT(a_wih,  awihP,  768, 128);
  packT(a_whh,  awhhP,  768, 256);
  packT(g1_wih, g1wihP, 768, 256);
  packT(g1_whh, g1whhP, 768, 256);
  packT(g2_wih, g2wihP, 768, 256);
  packT(g2_whh, g2whhP, 768, 256);

  packMem_kernel<<<(BB * MM * 128 + 255) / 256, 256, 0, stream>>>(mem, memB2);
  keys2_kernel<<<4096, 256, 0, stream>>>(mem, W1, key2);

  DP p;
  p.tf = tf;
  p.W2P = W2P; p.projP = projP; p.outP = outP;
  p.awihP = awihP; p.awhhP = awhhP;
  p.g1wihP = g1wihP; p.g1whhP = g1whhP; p.g2wihP = g2wihP; p.g2whhP = g2whhP;
  p.key2 = key2; p.memB2 = memB2;
  p.a_bih = a_bih; p.a_bhh = a_bhh; p.g1_bih = g1_bih; p.g1_bhh = g1_bhh;
  p.g2_bih = g2_bih; p.g2_bhh = g2_bhh;
  p.proj_b = proj_b; p.out_b = out_b; p.v = vw;
  p.out = (float*)d_out;

  decoder64<<<BB, 1024, 0, stream>>>(p);
}